// Round 3
// baseline (163.272 us; speedup 1.0000x reference)
//
#include <hip/hip_runtime.h>

#define POOL 7
#define NCH 256
#define OUT_PER_BOX (NCH * POOL * POOL)   // 12544 = 7 * 1792
#define PARTS 7
#define PART_SZ (OUT_PER_BOX / PARTS)     // 1792 = 7 * 256
#define ITERS (PART_SZ / 256)             // 7
#define NXCD 8
#define CAPB 192                           // max boxes per XCD range (8*192 >= 1000)
#define NBINS 64

// ---------------------------------------------------------------------------
// Kernel 1: counting-sort boxes into 64 bins = (level, 4x4 quadrant), then
// cost-balanced contiguous partition of the sorted list into 8 XCD ranges.
// Cost = estimated cache-line footprint; level-2 boxes weighted 2x (their bin
// working set exceeds the 4 MiB per-XCD L2 -> observed thrash in round 1).
// Single block; order within a bin is arbitrary (output indexed by orig id).
// ---------------------------------------------------------------------------
__global__ __launch_bounds__(1024) void bin_boxes_kernel(
    const float* __restrict__ boxes, int* __restrict__ perm,
    int* __restrict__ starts, int nbox)
{
    __shared__ int s_cnt[NBINS];
    __shared__ int s_off[NBINS];
    __shared__ int s_perm[1024];
    __shared__ int s_pfx[1024];
    __shared__ int s_start[NXCD + 1];
    const int i = threadIdx.x;

    if (i < NBINS) s_cnt[i] = 0;
    __syncthreads();

    int bin = -1, cost = 0;
    if (i < nbox) {
        const float y1 = boxes[i * 4 + 0];
        const float x1 = boxes[i * 4 + 1];
        const float y2 = boxes[i * 4 + 2];
        const float x2 = boxes[i * 4 + 3];
        const float h = y2 - y1;
        const float w = x2 - x1;
        const float lvlf = 4.0f + log2f(sqrtf(h * w) * (1.0f / 0.21875f));
        int lvl = (int)rintf(lvlf);
        lvl = lvl < 2 ? 2 : (lvl > 5 ? 5 : lvl);
        const int H = 256 >> (lvl - 2);

        const float cy = 0.5f * (y1 + y2);
        const float cx = 0.5f * (x1 + x2);
        int qy = (int)(cy * 4.0f); qy = qy < 0 ? 0 : (qy > 3 ? 3 : qy);
        int qx = (int)(cx * 4.0f); qx = qx < 0 ? 0 : (qx > 3 ? 3 : qx);
        bin = ((lvl - 2) << 4) | (qy << 2) | qx;

        // line-footprint cost model
        const float hpx = h * (float)(H - 1);
        const float wpx = w * (float)(H - 1);
        const float rows  = fminf(14.0f, hpx + 2.0f);
        const float lines = wpx * (4.0f / 64.0f) + 1.5f;
        float costf = rows * lines * (lvl == 2 ? 2.0f : 1.0f) + 10.0f;
        cost = (int)(costf * 4.0f);

        atomicAdd(&s_cnt[bin], 1);
    }
    __syncthreads();

    if (i == 0) {
        int acc = 0;
        for (int b = 0; b < NBINS; ++b) { s_off[b] = acc; acc += s_cnt[b]; }
    }
    __syncthreads();

    int pos = -1;
    if (i < nbox) {
        pos = atomicAdd(&s_off[bin], 1);
        s_perm[pos] = i;
    }
    __syncthreads();

    // cost in sorted order
    s_pfx[i] = 0;
    __syncthreads();
    if (pos >= 0) s_pfx[pos] = cost;
    __syncthreads();

    // inclusive prefix sum (Hillis-Steele, 1024)
    for (int d = 1; d < 1024; d <<= 1) {
        const int v = s_pfx[i] + (i >= d ? s_pfx[i - d] : 0);
        __syncthreads();
        s_pfx[i] = v;
        __syncthreads();
    }

    // find cost-split points: start[k] = first s with pfx_incl[s] >= k*T/8
    if (i < NXCD + 1) s_start[i] = (i == 0) ? 0 : nbox;
    __syncthreads();
    const int T = s_pfx[nbox - 1];
    if (i < nbox) {
        const int prev = (i > 0) ? s_pfx[i - 1] : 0;
        const int cur  = s_pfx[i];
        #pragma unroll
        for (int k = 1; k < NXCD; ++k) {
            const long long tk = ((long long)T * k) / NXCD;
            if (prev < tk && cur >= tk) s_start[k] = i + 1 > nbox ? nbox : i + 1;
        }
    }
    __syncthreads();

    if (i == 0) {
        // feasibility + monotone (forward), then cap enforcement (backward)
        for (int k = 1; k < NXCD; ++k) {
            int v = s_start[k];
            if (v < s_start[k - 1]) v = s_start[k - 1];
            const int lo = nbox - (NXCD - k) * CAPB;
            if (v < lo) v = lo;
            const int hi = k * CAPB;
            if (v > hi) v = hi;
            s_start[k] = v;
        }
        s_start[NXCD] = nbox;
        for (int k = NXCD - 1; k >= 1; --k) {
            const int need = s_start[k + 1] - CAPB;
            if (s_start[k] < need) s_start[k] = need;
        }
        #pragma unroll
        for (int k = 0; k <= NXCD; ++k) starts[k] = s_start[k];
    }

    if (i < nbox) perm[i] = s_perm[i];
}

// Fallback for nbox > 1024 (never hit with this harness): identity perm,
// equal-count ranges.
__global__ void identity_perm_kernel(int* __restrict__ perm,
                                     int* __restrict__ starts, int nbox) {
    const int i = blockIdx.x * blockDim.x + threadIdx.x;
    if (i < nbox) perm[i] = i;
    if (blockIdx.x == 0 && threadIdx.x <= NXCD) {
        starts[threadIdx.x] = (int)(((long long)nbox * threadIdx.x) / NXCD);
    }
}

// ---------------------------------------------------------------------------
// Kernel 2: ROI-align. Body identical to the verified round-0 kernel; mapping:
//   xcd = blockIdx % 8 (hardware round-robin), slot = blockIdx / 8
//   XCD k processes sorted boxes [starts[k], starts[k+1]) IN ORDER -> each
//   XCD walks its bins contiguously (round-1 locality) with cost-balanced
//   ranges (round-2 balance). Over-cap slots early-exit.
// ---------------------------------------------------------------------------
__global__ __launch_bounds__(256) void roi_align_kernel(
    const float* __restrict__ boxes,
    const float* __restrict__ p2,
    const float* __restrict__ p3,
    const float* __restrict__ p4,
    const float* __restrict__ p5,
    float* __restrict__ out,
    const int* __restrict__ perm,
    const int* __restrict__ starts)
{
    const int xcd  = blockIdx.x & (NXCD - 1);
    const int slot = blockIdx.x >> 3;
    const int l    = slot / PARTS;
    const int part = slot - l * PARTS;
    const int s    = starts[xcd] + l;
    if (s >= starts[xcd + 1]) return;
    const int n   = perm[s];
    const int tid = threadIdx.x;

    __shared__ int   s_y0[POOL], s_y1[POOL], s_xb[POOL], s_xcl[POOL];
    __shared__ float s_wy[POOL], s_wx[POOL], s_vy[POOL], s_vx[POOL];

    const float by1 = boxes[n * 4 + 0];
    const float bx1 = boxes[n * 4 + 1];
    const float by2 = boxes[n * 4 + 2];
    const float bx2 = boxes[n * 4 + 3];
    const float h = by2 - by1;
    const float w = bx2 - bx1;

    // roi_level = clip(round(4 + log2(sqrt(h*w) / (224/1024))), 2, 5)
    const float lvlf = 4.0f + log2f(sqrtf(h * w) / 0.21875f);
    int lvl = (int)rintf(lvlf);          // round-half-to-even, matches jnp.round
    lvl = lvl < 2 ? 2 : (lvl > 5 ? 5 : lvl);

    const float* fm;
    int H;
    switch (lvl) {
        case 2:  fm = p2; H = 256; break;
        case 3:  fm = p3; H = 128; break;
        case 4:  fm = p4; H = 64;  break;
        default: fm = p5; H = 32;  break;
    }
    const float Hm1 = (float)(H - 1);

    if (tid < POOL) {
        const float t7 = (float)tid * (1.0f / 6.0f);

        const float yy  = (by1 + h * t7) * Hm1;
        const float y0f = floorf(yy);
        int y0 = (int)y0f;
        y0 = min(H - 1, max(0, y0));
        s_y0[tid] = y0;
        s_y1[tid] = min(H - 1, y0 + 1);
        s_wy[tid] = yy - y0f;                       // weight from UNCLIPPED floor
        s_vy[tid] = (yy >= 0.0f && yy <= Hm1) ? 1.0f : 0.0f;

        const float xx  = (bx1 + w * t7) * Hm1;
        const float x0f = floorf(xx);
        int x0 = (int)x0f;
        x0 = min(H - 1, max(0, x0));
        // paired-load base: float2 at xb covers {xb, xb+1}.
        //   x0 <= H-2 : v00 = pair.x, v01 = pair.y   (x1 = x0+1)
        //   x0 == H-1 : v00 = v01 = pair.y           (x1 = x0, clamped)
        s_xb[tid]  = min(x0, H - 2);
        s_xcl[tid] = (x0 == H - 1) ? 1 : 0;
        s_wx[tid]  = xx - x0f;
        s_vx[tid]  = (xx >= 0.0f && xx <= Hm1) ? 1.0f : 0.0f;
    }
    __syncthreads();

    const size_t out_base = (size_t)n * OUT_PER_BOX + (size_t)part * PART_SZ;
    const int idx0 = part * PART_SZ + tid;
    const int HW = H * H;

    // Phase 1: issue all 14 dwordx2 gathers, keep results in registers.
    float2 q0[ITERS], q1[ITERS];
    #pragma unroll
    for (int i = 0; i < ITERS; ++i) {
        const int idx = idx0 + i * 256;
        const int cch = idx / 49;
        const int r   = idx - cch * 49;
        const int py  = r / 7;
        const int px  = r - py * 7;

        const float* fmc = fm + (size_t)cch * HW;
        const int xb = s_xb[px];
        q0[i] = *(const float2*)(fmc + s_y0[py] * H + xb);
        q1[i] = *(const float2*)(fmc + s_y1[py] * H + xb);
    }

    // Phase 2: lerp + store (coalesced).
    #pragma unroll
    for (int i = 0; i < ITERS; ++i) {
        const int idx = idx0 + i * 256;
        const int cch = idx / 49;
        const int r   = idx - cch * 49;
        const int py  = r / 7;
        const int px  = r - py * 7;

        const float wy = s_wy[py], wx = s_wx[px];
        const int   cl = s_xcl[px];

        const float v00 = cl ? q0[i].y : q0[i].x;
        const float v01 = q0[i].y;
        const float v10 = cl ? q1[i].y : q1[i].x;
        const float v11 = q1[i].y;

        const float r0 = v00 + wx * (v01 - v00);
        const float r1 = v10 + wx * (v11 - v10);
        float val = (r0 + wy * (r1 - r0)) * s_vy[py] * s_vx[px];

        out[out_base + (size_t)(i * 256 + tid)] = val;
    }
}

extern "C" void kernel_launch(void* const* d_in, const int* in_sizes, int n_in,
                              void* d_out, int out_size, void* d_ws, size_t ws_size,
                              hipStream_t stream) {
    const float* boxes = (const float*)d_in[0];
    const float* p2    = (const float*)d_in[1];
    const float* p3    = (const float*)d_in[2];
    const float* p4    = (const float*)d_in[3];
    const float* p5    = (const float*)d_in[4];
    float* out         = (float*)d_out;
    int*   perm        = (int*)d_ws;
    int*   starts      = (int*)((char*)d_ws + 8192);

    const int nbox = in_sizes[0] / 4;   // 1000

    if (nbox <= 1024) {
        bin_boxes_kernel<<<1, 1024, 0, stream>>>(boxes, perm, starts, nbox);
        roi_align_kernel<<<NXCD * CAPB * PARTS, 256, 0, stream>>>(
            boxes, p2, p3, p4, p5, out, perm, starts);
    } else {
        const int cap = (nbox + NXCD - 1) / NXCD;
        identity_perm_kernel<<<(nbox + 255) / 256, 256, 0, stream>>>(perm, starts, nbox);
        roi_align_kernel<<<NXCD * cap * PARTS, 256, 0, stream>>>(
            boxes, p2, p3, p4, p5, out, perm, starts);
    }
}